// Round 7
// baseline (82.885 us; speedup 1.0000x reference)
//
#include <hip/hip_runtime.h>
#include <hip/hip_bf16.h>

#define BDIM 16
#define HDIM 128
#define TDIM 4096

typedef __attribute__((ext_vector_type(8))) short bf16x8;
typedef __attribute__((ext_vector_type(4))) float f32x4;

// round-to-nearest-even fp32 -> bf16 (inputs are bounded cos/sin, no NaN)
static __device__ __forceinline__ unsigned int f2bf(float f) {
  unsigned int u = __float_as_uint(f);
  return (u + 0x7fffu + ((u >> 16) & 1u)) >> 16;
}

// ---------------------------------------------------------------------------
// Single fused kernel:
//   table-gen (all K=256 staged once, 64KB LDS) -> bf16 MFMA 64x64 tile GEMM
//   -> per-tile partial LSE -> in-LDS gather of this tile's samples -> out
//   -> last-block-per-batch folds partials to logZ and subtracts over out[b,:]
// logits[hi*256+lo] = sum_k U[k][hi]*V[k][lo], K=256:
//   U[2h][hi] = cos(s_hi), U[2h+1][hi] = -sin(s_hi), s_hi=<bits(hi),W[8:16]>
//   V[2h][lo] = cos(r+s_lo), V[2h+1][lo] = sin(r+s_lo), s_lo=<bits(lo),W[0:8]>
// grid = 16 batches * 16 tiles = 256 blocks (1 per CU), 512 threads (8 waves).
// ---------------------------------------------------------------------------
__global__ __launch_bounds__(512) void bide_main(
    const float* __restrict__ W, const float* __restrict__ r,
    const int* __restrict__ x, float* __restrict__ out,
    float* __restrict__ partM, float* __restrict__ partS,
    int* __restrict__ counter) {
  __shared__ unsigned int stg[2][64 * 128];  // staged U/V bf16 pairs, 64 KB
  __shared__ float ldsT[64 * 64];            // logits tile (swizzled), 16 KB
  __shared__ float red[16];
  __shared__ int s_last;

  int bid = blockIdx.x;
  int b    = bid >> 4;
  int tile = bid & 15;
  int tlo = (tile & 3) * 64;
  int thi = (tile >> 2) * 64;
  int tid = threadIdx.x;

  // staging role: tab 0 = U (hi side, W[8..15], no bias, -sin)
  //               tab 1 = V (lo side, W[0..7], bias r, +sin)
  int tab  = tid >> 8;
  int srow = tid & 63;
  int grp  = (tid >> 6) & 3;
  int sval = (tab ? tlo : thi) + srow;
  int woff = tab ? 0 : 8;
  int swz  = (srow & 7) << 2;       // u32-granularity XOR (== 16B-gran row&7)

  // compute role: wave w -> rows 16*(w&3), cols 32*(w>>2)
  int l = tid & 63;
  int w = tid >> 6;
  int rowblk = w & 3, colhalf = w >> 2;
  int r15 = l & 15, kl = l >> 4;
  int arow  = rowblk * 16 + r15;
  int brow0 = colhalf * 32 + r15;
  int brow1 = brow0 + 16;

  const float* Wb = W + b * HDIM * 16;
  const float* rb = r + b * HDIM;

  // preload this thread's x samples early (latency hides under table-gen)
  const int4* x4 = (const int4*)(x + b * TDIM);
  int4 xv0 = x4[tid];
  int4 xv1 = x4[tid + 512];

  // hoisted bit floats
  float fb[8];
#pragma unroll
  for (int n = 0; n < 8; ++n) fb[n] = (float)((sval >> n) & 1);

  // ---- stage ALL K=256 (128 h) in one pass: 32 sincos / thread ----
  unsigned int* stow = stg[tab];
#pragma unroll
  for (int kc = 0; kc < 4; ++kc) {
#pragma unroll
    for (int e = 0; e < 8; e += 2) {   // paired -> ds_write_b64
      int hp = grp * 8 + e;            // 0..31 within chunk (even)
      unsigned int uu0, uu1;
#pragma unroll
      for (int p = 0; p < 2; ++p) {
        int h = kc * 32 + hp + p;
        const float* Wp = Wb + h * 16 + woff;   // wave-uniform address
        float sacc = tab ? rb[h] : 0.f;
#pragma unroll
        for (int n = 0; n < 8; ++n) sacc = fmaf(fb[n], Wp[n], sacc);
        float sn, cs;
        __sincosf(sacc, &sn, &cs);
        if (!tab) sn = -sn;
        unsigned int uv = f2bf(cs) | (f2bf(sn) << 16);
        if (p == 0) uu0 = uv; else uu1 = uv;
      }
      int idx = srow * 128 + kc * 32 + (hp ^ swz);  // even -> 8B aligned
      *(uint2*)&stow[idx] = make_uint2(uu0, uu1);
    }
  }
  __syncthreads();

  // ---- 8 uninterrupted GEMM k-steps (16 MFMA / wave) ----
  f32x4 acc0 = {0.f, 0.f, 0.f, 0.f};
  f32x4 acc1 = {0.f, 0.f, 0.f, 0.f};
  const bf16x8* U8 = (const bf16x8*)stg[0];
  const bf16x8* V8 = (const bf16x8*)stg[1];
#pragma unroll
  for (int g = 0; g < 8; ++g) {
    int base = (g >> 1) * 8;
    int sl = (g & 1) * 4 + kl;
    bf16x8 a  = U8[arow  * 32 + base + (sl ^ (arow  & 7))];
    bf16x8 b0 = V8[brow0 * 32 + base + (sl ^ (brow0 & 7))];
    bf16x8 b1 = V8[brow1 * 32 + base + (sl ^ (brow1 & 7))];
    acc0 = __builtin_amdgcn_mfma_f32_16x16x32_bf16(a, b0, acc0, 0, 0, 0);
    acc1 = __builtin_amdgcn_mfma_f32_16x16x32_bf16(a, b1, acc1, 0, 0, 0);
  }

  // ---- stash tile to LDS, swizzled col-major:
  //      elem(row,col) at col*64 + (row ^ ((col&7)<<3)) ----
  {
    int c0  = colhalf * 32 + r15;
    int rb0 = rowblk * 16 + 4 * kl;
    int sw  = (c0 & 7) << 3;          // same for c0 and c0+16
    *(f32x4*)&ldsT[c0 * 64 + (rb0 ^ sw)]        = acc0;
    *(f32x4*)&ldsT[(c0 + 16) * 64 + (rb0 ^ sw)] = acc1;
  }

  // ---- per-tile partial logsumexp from registers ----
  float m = fmaxf(fmaxf(fmaxf(acc0[0], acc0[1]), fmaxf(acc0[2], acc0[3])),
                  fmaxf(fmaxf(acc1[0], acc1[1]), fmaxf(acc1[2], acc1[3])));
#pragma unroll
  for (int off = 1; off < 64; off <<= 1) m = fmaxf(m, __shfl_xor(m, off, 64));
  if (l == 0) red[w] = m;
  __syncthreads();                    // red max ready; ldsT complete
  float M = red[0];
#pragma unroll
  for (int i = 1; i < 8; ++i) M = fmaxf(M, red[i]);
  float s = 0.f;
#pragma unroll
  for (int q = 0; q < 4; ++q)
    s += __expf(acc0[q] - M) + __expf(acc1[q] - M);
#pragma unroll
  for (int off = 1; off < 64; off <<= 1) s += __shfl_xor(s, off, 64);
  if (l == 0) red[8 + w] = s;
  __syncthreads();
  if (tid == 0) {
    float S = 0.f;
#pragma unroll
    for (int i = 0; i < 8; ++i) S += red[8 + i];
    partM[bid] = M;
    partS[bid] = S;
  }

  // ---- serve samples landing in this tile (unnormalized logit) ----
  float* ob = out + b * TDIM;
#pragma unroll
  for (int it = 0; it < 2; ++it) {
    int4 xv = it ? xv1 : xv0;
    int tbase = 4 * (tid + it * 512);
    int vv[4] = {xv.x, xv.y, xv.z, xv.w};
#pragma unroll
    for (int j = 0; j < 4; ++j) {
      int v = vv[j];
      int tl = ((v >> 14) << 2) | ((v >> 6) & 3);
      if (tl == tile) {
        int row = (v >> 8) & 63, col = v & 63;
        ob[tbase + j] = ldsT[col * 64 + (row ^ ((col & 7) << 3))];
      }
    }
  }

  // ---- last block of this batch: fold partials -> logZ, subtract ----
  __syncthreads();                    // all out + partM/S writes issued
  if (tid == 0) {
    __threadfence();                  // release our writes device-wide
    s_last = (atomicAdd(&counter[b], 1) == 15);
  }
  __syncthreads();
  if (s_last) {
    __threadfence();                  // acquire other blocks' writes
    float Mz = -1e30f;
#pragma unroll
    for (int i = 0; i < 16; ++i) Mz = fmaxf(Mz, partM[b * 16 + i]);
    float Sz = 0.f;
#pragma unroll
    for (int i = 0; i < 16; ++i)
      Sz += partS[b * 16 + i] * __expf(partM[b * 16 + i] - Mz);
    float logZ = Mz + __logf(Sz);
    float4* o4b = (float4*)(out + b * TDIM);
#pragma unroll
    for (int it = 0; it < 2; ++it) {
      float4 v = o4b[tid + it * 512];
      v.x -= logZ; v.y -= logZ; v.z -= logZ; v.w -= logZ;
      o4b[tid + it * 512] = v;
    }
  }
}

// ---------------------------------------------------------------------------
extern "C" void kernel_launch(void* const* d_in, const int* in_sizes, int n_in,
                              void* d_out, int out_size, void* d_ws, size_t ws_size,
                              hipStream_t stream) {
  const int*   x = (const int*)d_in[0];     // [16][4096] int32 bit patterns
  const float* W = (const float*)d_in[1];   // [16][128][16]
  const float* r = (const float*)d_in[2];   // [16][128]
  float* out = (float*)d_out;               // [16][4096] fp32

  float* partM   = (float*)d_ws;            // 256 floats
  float* partS   = partM + 256;             // 256 floats
  int*   counter = (int*)(partS + 256);     // 16 ints (must start at 0)

  hipMemsetAsync(counter, 0, BDIM * sizeof(int), stream);
  bide_main<<<BDIM * 16, 512, 0, stream>>>(W, r, x, out, partM, partS, counter);
}

// Round 8
// 69.046 us; speedup vs baseline: 1.2004x; 1.2004x over previous
//
#include <hip/hip_runtime.h>
#include <hip/hip_bf16.h>

#define BDIM 16
#define HDIM 128
#define TDIM 4096
#define VSZ  65536

typedef __attribute__((ext_vector_type(8))) short bf16x8;
typedef __attribute__((ext_vector_type(4))) float f32x4;

// round-to-nearest-even fp32 -> bf16 (inputs are bounded cos/sin, no NaN)
static __device__ __forceinline__ unsigned int f2bf(float f) {
  unsigned int u = __float_as_uint(f);
  return (u + 0x7fffu + ((u >> 16) & 1u)) >> 16;
}

// ---------------------------------------------------------------------------
// K1: fused table-gen + bf16-MFMA tile GEMM + per-tile partial LSE
//     + in-LDS gather of this tile's samples (writes logit_x to out).
// logits[hi*256+lo] = sum_k U[k][hi]*V[k][lo], K=256:
//   U[2h][hi] = cos(s_hi), U[2h+1][hi] = -sin(s_hi), s_hi=<bits(hi),W[8:16]>
//   V[2h][lo] = cos(r+s_lo), V[2h+1][lo] = sin(r+s_lo), s_lo=<bits(lo),W[0:8]>
// Tile 64(hi)x64(lo), 512 threads (8 waves). No logits in global memory:
// the tile lives in LDS; each block scans x[b,:] and serves the samples
// whose pattern falls inside its tile (each v belongs to exactly one tile).
// K staged in 4 chunks of 32 h (16 KB) to keep VGPR pressure low (R7 lesson:
// whole-K unrolled staging spilled to scratch, +13us).
// grid = 16 batches * 16 tiles = 256 blocks (1 per CU).
// ---------------------------------------------------------------------------
__global__ __launch_bounds__(512) void bide_main(
    const float* __restrict__ W, const float* __restrict__ r,
    const int* __restrict__ x, float* __restrict__ out,
    float* __restrict__ partM, float* __restrict__ partS) {
  __shared__ unsigned int stg[2][64 * 32];  // staged U/V bf16 pairs, 16 KB
  __shared__ float ldsT[64 * 64];           // logits tile (swizzled), 16 KB
  __shared__ float red[16];

  int bid = blockIdx.x;
  int b    = bid >> 4;
  int tile = bid & 15;
  int tlo = (tile & 3) * 64;
  int thi = (tile >> 2) * 64;
  int tid = threadIdx.x;

  // staging role: tab 0 = U (hi side, W[8..15], no bias, -sin)
  //               tab 1 = V (lo side, W[0..7], bias r, +sin)
  int tab  = tid >> 8;
  int srow = tid & 63;
  int grp  = (tid >> 6) & 3;
  int sval = (tab ? tlo : thi) + srow;
  int woff = tab ? 0 : 8;
  int swz  = (srow & 7) << 2;       // u32-granularity XOR (== 16B-gran row&7)

  // compute role: wave w -> rows 16*(w&3), cols 32*(w>>2)
  int l = tid & 63;
  int w = tid >> 6;
  int rowblk = w & 3, colhalf = w >> 2;
  int r15 = l & 15, kl = l >> 4;
  int arow  = rowblk * 16 + r15;
  int brow0 = colhalf * 32 + r15;
  int brow1 = brow0 + 16;

  const float* Wb = W + b * HDIM * 16;
  const float* rb = r + b * HDIM;

  // hoist bit floats (loop-invariant per thread)
  float fb[8];
#pragma unroll
  for (int n = 0; n < 8; ++n) fb[n] = (float)((sval >> n) & 1);

  f32x4 acc0 = {0.f, 0.f, 0.f, 0.f};
  f32x4 acc1 = {0.f, 0.f, 0.f, 0.f};

  const bf16x8* U8 = (const bf16x8*)stg[0];
  const bf16x8* V8 = (const bf16x8*)stg[1];
  unsigned int* stow = stg[tab];

  for (int kc = 0; kc < 4; ++kc) {   // 4 chunks of 32 h (= 64 k)
    int hbase = kc * 32;
    __syncthreads();                 // prev chunk's frag reads done
#pragma unroll
    for (int e = 0; e < 8; e += 2) { // paired -> ds_write_b64
      int hp = grp * 8 + e;
      unsigned int uu0, uu1;
#pragma unroll
      for (int p = 0; p < 2; ++p) {
        int h = hbase + hp + p;
        const float* Wp = Wb + h * 16 + woff;   // wave-uniform address
        float sacc = tab ? rb[h] : 0.f;
#pragma unroll
        for (int n = 0; n < 8; ++n) sacc = fmaf(fb[n], Wp[n], sacc);
        float sn, cs;
        __sincosf(sacc, &sn, &cs);
        if (!tab) sn = -sn;
        unsigned int uv = f2bf(cs) | (f2bf(sn) << 16);
        if (p == 0) uu0 = uv; else uu1 = uv;
      }
      int idx = srow * 32 + (hp ^ swz);  // hp even, swz bits 2-4 -> idx even
      *(uint2*)&stow[idx] = make_uint2(uu0, uu1);
    }
    __syncthreads();

#pragma unroll
    for (int ks = 0; ks < 2; ++ks) { // 2 k-steps of 32 per chunk
      bf16x8 a  = U8[arow  * 8 + ((ks * 4 + kl) ^ (arow  & 7))];
      bf16x8 b0 = V8[brow0 * 8 + ((ks * 4 + kl) ^ (brow0 & 7))];
      bf16x8 b1 = V8[brow1 * 8 + ((ks * 4 + kl) ^ (brow1 & 7))];
      acc0 = __builtin_amdgcn_mfma_f32_16x16x32_bf16(a, b0, acc0, 0, 0, 0);
      acc1 = __builtin_amdgcn_mfma_f32_16x16x32_bf16(a, b1, acc1, 0, 0, 0);
    }
  }

  // ---- stash tile to LDS, swizzled col-major: elem(row,col) at
  //      col*64 + (row ^ ((col&7)<<3)); float4-contiguous in row ----
  {
    int c0  = colhalf * 32 + r15;
    int rb0 = rowblk * 16 + 4 * kl;
    int sw  = (c0 & 7) << 3;          // same for c0 and c0+16
    *(f32x4*)&ldsT[c0 * 64 + (rb0 ^ sw)]        = acc0;
    *(f32x4*)&ldsT[(c0 + 16) * 64 + (rb0 ^ sw)] = acc1;
  }

  // ---- per-tile partial logsumexp from registers ----
  float m = fmaxf(fmaxf(fmaxf(acc0[0], acc0[1]), fmaxf(acc0[2], acc0[3])),
                  fmaxf(fmaxf(acc1[0], acc1[1]), fmaxf(acc1[2], acc1[3])));
#pragma unroll
  for (int off = 1; off < 64; off <<= 1) m = fmaxf(m, __shfl_xor(m, off, 64));
  if (l == 0) red[w] = m;
  __syncthreads();                    // red ready; also ldsT complete
  float M = red[0];
#pragma unroll
  for (int i = 1; i < 8; ++i) M = fmaxf(M, red[i]);
  float s = 0.f;
#pragma unroll
  for (int q = 0; q < 4; ++q)
    s += __expf(acc0[q] - M) + __expf(acc1[q] - M);
#pragma unroll
  for (int off = 1; off < 64; off <<= 1) s += __shfl_xor(s, off, 64);
  if (l == 0) red[8 + w] = s;
  __syncthreads();
  if (tid == 0) {
    float S = 0.f;
#pragma unroll
    for (int i = 0; i < 8; ++i) S += red[8 + i];
    partM[bid] = M;
    partS[bid] = S;
  }

  // ---- scan x[b,:]; serve samples landing in this tile ----
  const int4* x4 = (const int4*)(x + b * TDIM);
  float* ob = out + b * TDIM;
#pragma unroll
  for (int it = 0; it < 2; ++it) {
    int4 xv = x4[tid + it * 512];
    int tbase = 4 * (tid + it * 512);
    int vv[4] = {xv.x, xv.y, xv.z, xv.w};
#pragma unroll
    for (int j = 0; j < 4; ++j) {
      int v = vv[j];
      int tl = ((v >> 14) << 2) | ((v >> 6) & 3);
      if (tl == tile) {
        int row = (v >> 8) & 63, col = v & 63;
        ob[tbase + j] = ldsT[col * 64 + (row ^ ((col & 7) << 3))];
      }
    }
  }
}

// ---------------------------------------------------------------------------
// K2: logZ from the 16 tile-partials (uniform per block), out -= logZ.
// grid = 64 blocks (4 segments x 16 batches), 256 threads, float4 each.
// ---------------------------------------------------------------------------
__global__ __launch_bounds__(256) void bide_sub(
    float* __restrict__ out, const float* __restrict__ partM,
    const float* __restrict__ partS) {
  int bid = blockIdx.x;
  int b = bid >> 2, seg = bid & 3;
  float M = -1e30f;
#pragma unroll
  for (int i = 0; i < 16; ++i) M = fmaxf(M, partM[b * 16 + i]);
  float S = 0.f;
#pragma unroll
  for (int i = 0; i < 16; ++i)
    S += partS[b * 16 + i] * __expf(partM[b * 16 + i] - M);
  float logZ = M + __logf(S);
  float4* o4 = (float4*)(out + b * TDIM + seg * 1024);
  float4 v = o4[threadIdx.x];
  v.x -= logZ; v.y -= logZ; v.z -= logZ; v.w -= logZ;
  o4[threadIdx.x] = v;
}

// ---------------------------------------------------------------------------
extern "C" void kernel_launch(void* const* d_in, const int* in_sizes, int n_in,
                              void* d_out, int out_size, void* d_ws, size_t ws_size,
                              hipStream_t stream) {
  const int*   x = (const int*)d_in[0];     // [16][4096] int32 bit patterns
  const float* W = (const float*)d_in[1];   // [16][128][16]
  const float* r = (const float*)d_in[2];   // [16][128]
  float* out = (float*)d_out;               // [16][4096] fp32

  float* partM = (float*)d_ws;              // 256 floats
  float* partS = partM + 256;               // 256 floats

  bide_main<<<BDIM * 16, 512, 0, stream>>>(W, r, x, out, partM, partS);
  bide_sub<<<64, 256, 0, stream>>>(out, partM, partS);
}